// Round 1
// 398.762 us; speedup vs baseline: 1.0989x; 1.0989x over previous
//
#include <hip/hip_runtime.h>

#define DIN 128
#define NHEADS 4
#define CH 32
#define MT 128          // GEMM rows per block
#define CHUNK 4096      // node-scan chunk per block
#define NPB 256         // nodes per bucket (bucket = dst >> 8)
#define EPB_IT 25       // edges per thread in bucket_scatter (block: 6400)

#define ST_H 136        // fp16 staging row stride (halves): 272B, 16B-aligned rows
#define ST_F 132        // fp32 staging row stride (floats): 528B, 16B-aligned rows

typedef _Float16 h8 __attribute__((ext_vector_type(8)));
typedef float f4 __attribute__((ext_vector_type(4)));

// ---------------------------------------------------------------------------
// prep: W[k][n] fp32 -> Wt[mat][n][k] fp16
// ---------------------------------------------------------------------------
__global__ __launch_bounds__(256) void prep_w(
    const float* __restrict__ Wq, const float* __restrict__ Wk,
    const float* __restrict__ Wv, const float* __restrict__ Wsk,
    _Float16* __restrict__ wt)
{
    int i = blockIdx.x * 256 + threadIdx.x;
    if (i >= 4 * 16384) return;
    int mat = i >> 14;
    int rem = i & 16383;
    int n  = rem >> 7;
    int kk = rem & 127;
    const float* W = (mat == 0) ? Wq : (mat == 1) ? Wk : (mat == 2) ? Wv : Wsk;
    wt[i] = (_Float16)W[kk * 128 + n];
}

// ---------------------------------------------------------------------------
// Kernel 1: fused MFMA GEMM for all 4 mats in one block.
//   - A tile loaded once (fp32 x converted inline -> no separate cvt_x pass)
//   - A fragments hoisted to registers, LDS reused as epilogue staging buffer
//   - epilogue: stage tile in LDS, emit coalesced vector stores
//   mats 1/2 write interleaved kv rows (group g: 4 k-halves | 4 v-halves).
// ---------------------------------------------------------------------------
__global__ __launch_bounds__(256) void qkvs_all(
    const float* __restrict__ x, const _Float16* __restrict__ wt,
    const float* __restrict__ bq, const float* __restrict__ bk,
    const float* __restrict__ bv, const float* __restrict__ bsk,
    _Float16* __restrict__ qh, _Float16* __restrict__ kvh,
    float* __restrict__ outskip, int N)
{
    __shared__ _Float16 Sbuf[17408];     // 34.8 KB: A-tile (32 KB) then staging
    const int t = threadIdx.x;
    const int rowBase = blockIdx.x * MT;

    // ---- load A tile (fp32 -> fp16, XOR-swizzled, stride 128) ----
    for (int i = t; i < MT * 16; i += 256) {
        int r  = i >> 4;
        int c8 = i & 15;
        int gr = rowBase + r;
        _Float16 h[8];
        if (gr < N) {
            float4 f0 = reinterpret_cast<const float4*>(x)[(size_t)gr * 32 + c8 * 2];
            float4 f1 = reinterpret_cast<const float4*>(x)[(size_t)gr * 32 + c8 * 2 + 1];
            h[0] = (_Float16)f0.x; h[1] = (_Float16)f0.y;
            h[2] = (_Float16)f0.z; h[3] = (_Float16)f0.w;
            h[4] = (_Float16)f1.x; h[5] = (_Float16)f1.y;
            h[6] = (_Float16)f1.z; h[7] = (_Float16)f1.w;
        } else {
            #pragma unroll
            for (int j = 0; j < 8; ++j) h[j] = (_Float16)0.f;
        }
        *reinterpret_cast<uint4*>(&Sbuf[r * 128 + ((c8 ^ (r & 7)) << 3)]) =
            *reinterpret_cast<uint4*>(h);
    }
    __syncthreads();

    const int wid  = t >> 6;
    const int l    = t & 63;
    const int lm   = l & 15;
    const int quad = l >> 4;

    // ---- hoist A fragments to registers; Sbuf becomes free for staging ----
    h8 afrag[2][4];
    #pragma unroll
    for (int kq = 0; kq < 4; ++kq) {
        int c8 = kq * 4 + quad;
        afrag[0][kq] = *reinterpret_cast<const h8*>(
            &Sbuf[(wid * 32 + lm) * 128 + ((c8 ^ (lm & 7)) << 3)]);
        afrag[1][kq] = *reinterpret_cast<const h8*>(
            &Sbuf[(wid * 32 + 16 + lm) * 128 + ((c8 ^ (lm & 7)) << 3)]);
    }
    __syncthreads();   // all waves done reading A-tile before staging overwrites

    for (int mat = 0; mat < 4; ++mat) {
        const _Float16* __restrict__ Bsrc = wt + (size_t)mat * 16384;

        f4 acc[2][8];
        #pragma unroll
        for (int ms = 0; ms < 2; ++ms)
            #pragma unroll
            for (int nt = 0; nt < 8; ++nt)
                acc[ms][nt] = (f4){0.f, 0.f, 0.f, 0.f};

        #pragma unroll
        for (int kq = 0; kq < 4; ++kq) {
            const int k0 = (kq * 4 + quad) << 3;
            #pragma unroll
            for (int nt = 0; nt < 8; ++nt) {
                h8 b = *reinterpret_cast<const h8*>(
                    &Bsrc[(size_t)(nt * 16 + lm) * 128 + k0]);
                acc[0][nt] = __builtin_amdgcn_mfma_f32_16x16x32_f16(afrag[0][kq], b, acc[0][nt], 0, 0, 0);
                acc[1][nt] = __builtin_amdgcn_mfma_f32_16x16x32_f16(afrag[1][kq], b, acc[1][nt], 0, 0, 0);
            }
        }

        const float* bias = (mat == 0) ? bq : (mat == 1) ? bk : (mat == 2) ? bv : bsk;

        if (mat < 3) {
            // ---- stage fp16 tile [128][ST_H] ----
            #pragma unroll
            for (int ms = 0; ms < 2; ++ms) {
                #pragma unroll
                for (int nt = 0; nt < 8; ++nt) {
                    int col = nt * 16 + lm;
                    float bsv = bias[col];
                    int row = wid * 32 + ms * 16 + quad * 4;
                    #pragma unroll
                    for (int i2 = 0; i2 < 4; ++i2)
                        Sbuf[(row + i2) * ST_H + col] = (_Float16)(acc[ms][nt][i2] + bsv);
                }
            }
            __syncthreads();
            if (mat == 0) {
                // qh: 128 rows x 16 uint4, fully coalesced
                for (int j = t; j < 2048; j += 256) {
                    int r  = j >> 4;
                    int c0 = (j & 15) << 3;
                    int gr = rowBase + r;
                    if (gr < N)
                        *reinterpret_cast<uint4*>(&qh[(size_t)gr * 128 + c0]) =
                            *reinterpret_cast<const uint4*>(&Sbuf[r * ST_H + c0]);
                }
            } else {
                // kvh interleave: per row 32 uint2 chunks at stride 16B
                const int koff = (mat == 2) ? 4 : 0;
                for (int j = t; j < 4096; j += 256) {
                    int r = j >> 5;
                    int g = j & 31;
                    int gr = rowBase + r;
                    if (gr < N)
                        *reinterpret_cast<uint2*>(&kvh[(size_t)gr * 256 + g * 8 + koff]) =
                            *reinterpret_cast<const uint2*>(&Sbuf[r * ST_H + g * 4]);
                }
            }
            __syncthreads();   // staging buffer reused next mat
        } else {
            // ---- skip output is fp32: stage 64 rows per pass (2 passes) ----
            float* Sf = reinterpret_cast<float*>(Sbuf);
            #pragma unroll
            for (int p = 0; p < 2; ++p) {
                if ((wid >> 1) == p) {
                    int lrow = (wid & 1) * 32;
                    #pragma unroll
                    for (int ms = 0; ms < 2; ++ms) {
                        #pragma unroll
                        for (int nt = 0; nt < 8; ++nt) {
                            int col = nt * 16 + lm;
                            float bsv = bias[col];
                            int row = lrow + ms * 16 + quad * 4;
                            #pragma unroll
                            for (int i2 = 0; i2 < 4; ++i2)
                                Sf[(row + i2) * ST_F + col] = acc[ms][nt][i2] + bsv;
                        }
                    }
                }
                __syncthreads();
                for (int j = t; j < 2048; j += 256) {
                    int r  = j >> 5;
                    int c0 = (j & 31) << 2;
                    int gr = rowBase + p * 64 + r;
                    if (gr < N)
                        *reinterpret_cast<float4*>(&outskip[(size_t)gr * 128 + c0]) =
                            *reinterpret_cast<const float4*>(&Sf[r * ST_F + c0]);
                }
                __syncthreads();
            }
        }
    }
}

// ---------------------------------------------------------------------------
// Bucketed CSR build.  bucket b = nodes [b*256, b*256+256)
// ---------------------------------------------------------------------------
// Pass A: bucket histogram (LDS, then one global atomic per bucket per block)
__global__ __launch_bounds__(256) void bucket_hist(
    const int* __restrict__ ei, int* __restrict__ bcnt, int E, int nb)
{
    __shared__ int lds[512];
    for (int b = threadIdx.x; b < nb; b += 256) lds[b] = 0;
    __syncthreads();
    for (long long i = (long long)blockIdx.x * 256 + threadIdx.x; i < E;
         i += (long long)gridDim.x * 256)
        atomicAdd(&lds[ei[(size_t)E + i] >> 8], 1);
    __syncthreads();
    for (int b = threadIdx.x; b < nb; b += 256)
        if (lds[b]) atomicAdd(&bcnt[b], lds[b]);
}

// Pass A2: exclusive scan of bucket counts (1 block, nb <= 512)
__global__ __launch_bounds__(512) void scan_buckets(
    const int* __restrict__ bcnt, int* __restrict__ boff,
    int* __restrict__ bcur, int nb)
{
    __shared__ int ws[8];
    int t = threadIdx.x, lane = t & 63, wid = t >> 6;
    int v = (t < nb) ? bcnt[t] : 0;
    int s = v;
    #pragma unroll
    for (int off = 1; off < 64; off <<= 1) {
        int n = __shfl_up(s, off);
        if (lane >= off) s += n;
    }
    if (lane == 63) ws[wid] = s;
    __syncthreads();
    int add = 0;
    for (int w = 0; w < wid; ++w) add += ws[w];
    int excl = s - v + add;
    if (t < nb) { boff[t] = excl; bcur[t] = excl; }
    if (t == nb - 1) boff[nb] = excl + v;
}

// Pass B: scatter (src,dst) pairs into bucket regions, coalesced runs.
__global__ __launch_bounds__(256) void bucket_scatter(
    const int* __restrict__ ei, int* __restrict__ bcur,
    uint2* __restrict__ pairs, int E, int nb)
{
    __shared__ int cnt[512];
    int t = threadIdx.x;
    for (int b = t; b < nb; b += 256) cnt[b] = 0;
    __syncthreads();

    long long e0 = (long long)blockIdx.x * (256 * EPB_IT);
    int ps[EPB_IT], pd[EPB_IT];
    #pragma unroll
    for (int j = 0; j < EPB_IT; ++j) {
        long long e = e0 + j * 256 + t;
        if (e < E) {
            ps[j] = ei[e];
            pd[j] = ei[(size_t)E + e];
            atomicAdd(&cnt[pd[j] >> 8], 1);
        } else pd[j] = -1;
    }
    __syncthreads();
    // reserve contiguous range per bucket; cnt[b] becomes this block's cursor
    for (int b = t; b < nb; b += 256) {
        int c = cnt[b];
        if (c) cnt[b] = atomicAdd(&bcur[b], c);
    }
    __syncthreads();
    #pragma unroll
    for (int j = 0; j < EPB_IT; ++j) {
        if (pd[j] >= 0) {
            int pos = atomicAdd(&cnt[pd[j] >> 8], 1);
            pairs[pos] = make_uint2((unsigned)ps[j], (unsigned)pd[j]);
        }
    }
}

// Pass C: per-node counts from bucketed pairs (LDS only, no global atomics)
__global__ __launch_bounds__(256) void bucket_counts(
    const uint2* __restrict__ pairs, const int* __restrict__ boff,
    int* __restrict__ counts, int N)
{
    __shared__ int cnt[NPB];
    int b = blockIdx.x, t = threadIdx.x;
    cnt[t] = 0;
    __syncthreads();
    int s = boff[b], e = boff[b + 1];
    for (int i = s + t; i < e; i += 256)
        atomicAdd(&cnt[pairs[i].y & (NPB - 1)], 1);
    __syncthreads();
    int node = b * NPB + t;
    if (node < N) counts[node] = cnt[t];
}

// node-level scan (3 kernels, unchanged structure)
__global__ __launch_bounds__(256) void chunk_sums(
    const int* __restrict__ counts, int* __restrict__ partials, int N)
{
    int b = blockIdx.x, t = threadIdx.x;
    int base = b * CHUNK + t * 16;
    int s = 0;
    #pragma unroll
    for (int j = 0; j < 16; ++j) {
        int i = base + j;
        if (i < N) s += counts[i];
    }
    #pragma unroll
    for (int off = 1; off < 64; off <<= 1) s += __shfl_xor(s, off);
    __shared__ int ws[4];
    int lane = t & 63, wid = t >> 6;
    if (lane == 0) ws[wid] = s;
    __syncthreads();
    if (t == 0) partials[b] = ws[0] + ws[1] + ws[2] + ws[3];
}

__global__ __launch_bounds__(256) void scan_chunks(
    const int* __restrict__ partials, int* __restrict__ chunkoff, int nch)
{
    __shared__ int ws[4];
    int t = threadIdx.x, lane = t & 63, wid = t >> 6;
    int v = (t < nch) ? partials[t] : 0;
    int s = v;
    #pragma unroll
    for (int off = 1; off < 64; off <<= 1) {
        int n = __shfl_up(s, off);
        if (lane >= off) s += n;
    }
    if (lane == 63) ws[wid] = s;
    __syncthreads();
    int add = 0;
    for (int w = 0; w < wid; ++w) add += ws[w];
    if (t < nch) chunkoff[t] = s - v + add;
}

__global__ __launch_bounds__(256) void scan_write(
    const int* __restrict__ counts, const int* __restrict__ chunkoff,
    int* __restrict__ rowptr, int N)
{
    int b = blockIdx.x, t = threadIdx.x;
    int base = b * CHUNK + t * 16;
    int vals[16];
    int s = 0;
    #pragma unroll
    for (int j = 0; j < 16; ++j) {
        int i = base + j;
        vals[j] = (i < N) ? counts[i] : 0;
        s += vals[j];
    }
    int lane = t & 63, wid = t >> 6;
    int incl = s;
    #pragma unroll
    for (int off = 1; off < 64; off <<= 1) {
        int n = __shfl_up(incl, off);
        if (lane >= off) incl += n;
    }
    __shared__ int ws[4];
    if (lane == 63) ws[wid] = incl;
    __syncthreads();
    int add = chunkoff[b];
    for (int w = 0; w < wid; ++w) add += ws[w];
    int run = incl - s + add;
    #pragma unroll
    for (int j = 0; j < 16; ++j) {
        int i = base + j;
        if (i < N) rowptr[i + 1] = run + vals[j];
        run += vals[j];
    }
    if (b == 0 && t == 0) rowptr[0] = 0;
}

// Pass D: final placement; cursors in LDS, writes land in bucket's ~16KB window
__global__ __launch_bounds__(256) void bucket_place(
    const uint2* __restrict__ pairs, const int* __restrict__ boff,
    const int* __restrict__ rowptr, int* __restrict__ sorted, int N)
{
    __shared__ int cur[NPB];
    int b = blockIdx.x, t = threadIdx.x;
    int node = b * NPB + t;
    cur[t] = (node < N) ? rowptr[node] : 0;
    __syncthreads();
    int s = boff[b], e = boff[b + 1];
    for (int i = s + t; i < e; i += 256) {
        uint2 pr = pairs[i];
        int pos = atomicAdd(&cur[pr.y & (NPB - 1)], 1);
        sorted[pos] = (int)pr.x;
    }
}

// ---------------------------------------------------------------------------
// Kernel 4: fused logits + softmax + aggregation. 4-edge unroll for MLP.
// ---------------------------------------------------------------------------
__device__ inline float4 cvt4(uint2 r) {
    union { uint2 u; _Float16 h[4]; } c;
    c.u = r;
    return make_float4((float)c.h[0], (float)c.h[1], (float)c.h[2], (float)c.h[3]);
}

__global__ __launch_bounds__(256) void node_aggregate(
    const _Float16* __restrict__ q, const _Float16* __restrict__ kv,
    const int* __restrict__ rowptr, const int* __restrict__ srcs,
    float* __restrict__ out, int N)
{
    int gid  = blockIdx.x * 256 + threadIdx.x;
    int node = gid >> 5;
    if (node >= N) return;
    int l = gid & 31;

    float4 qv = cvt4(reinterpret_cast<const uint2*>(q + (size_t)node * 128)[l]);
    float4 acc = make_float4(0.f, 0.f, 0.f, 0.f);
    float z = 0.f;

    const uint4* kv4 = reinterpret_cast<const uint4*>(kv);
    const float SC = 0.17677669529663687f;   // 1/sqrt(32)
    int e0 = rowptr[node], e1 = rowptr[node + 1];
    int e = e0;
    for (; e + 4 <= e1; e += 4) {
        int s0 = srcs[e], s1 = srcs[e + 1], s2 = srcs[e + 2], s3 = srcs[e + 3];
        uint4 r0 = kv4[(size_t)s0 * 32 + l];
        uint4 r1 = kv4[(size_t)s1 * 32 + l];
        uint4 r2 = kv4[(size_t)s2 * 32 + l];
        uint4 r3 = kv4[(size_t)s3 * 32 + l];
        float4 k0 = cvt4(make_uint2(r0.x, r0.y)), v0 = cvt4(make_uint2(r0.z, r0.w));
        float4 k1 = cvt4(make_uint2(r1.x, r1.y)), v1 = cvt4(make_uint2(r1.z, r1.w));
        float4 k2 = cvt4(make_uint2(r2.x, r2.y)), v2 = cvt4(make_uint2(r2.z, r2.w));
        float4 k3 = cvt4(make_uint2(r3.x, r3.y)), v3 = cvt4(make_uint2(r3.z, r3.w));
        float sa = qv.x * k0.x + qv.y * k0.y + qv.z * k0.z + qv.w * k0.w;
        float sb = qv.x * k1.x + qv.y * k1.y + qv.z * k1.z + qv.w * k1.w;
        float sc = qv.x * k2.x + qv.y * k2.y + qv.z * k2.z + qv.w * k2.w;
        float sd = qv.x * k3.x + qv.y * k3.y + qv.z * k3.z + qv.w * k3.w;
        sa += __shfl_xor(sa, 1); sb += __shfl_xor(sb, 1);
        sc += __shfl_xor(sc, 1); sd += __shfl_xor(sd, 1);
        sa += __shfl_xor(sa, 2); sb += __shfl_xor(sb, 2);
        sc += __shfl_xor(sc, 2); sd += __shfl_xor(sd, 2);
        sa += __shfl_xor(sa, 4); sb += __shfl_xor(sb, 4);
        sc += __shfl_xor(sc, 4); sd += __shfl_xor(sd, 4);
        float pa = __expf(sa * SC), pb = __expf(sb * SC);
        float pc = __expf(sc * SC), pdd = __expf(sd * SC);
        z += (pa + pb) + (pc + pdd);
        acc.x += pa * v0.x + pb * v1.x + pc * v2.x + pdd * v3.x;
        acc.y += pa * v0.y + pb * v1.y + pc * v2.y + pdd * v3.y;
        acc.z += pa * v0.z + pb * v1.z + pc * v2.z + pdd * v3.z;
        acc.w += pa * v0.w + pb * v1.w + pc * v2.w + pdd * v3.w;
    }
    for (; e < e1; ++e) {
        int s0 = srcs[e];
        uint4 r0 = kv4[(size_t)s0 * 32 + l];
        float4 k0 = cvt4(make_uint2(r0.x, r0.y)), v0 = cvt4(make_uint2(r0.z, r0.w));
        float sa = qv.x * k0.x + qv.y * k0.y + qv.z * k0.z + qv.w * k0.w;
        sa += __shfl_xor(sa, 1);
        sa += __shfl_xor(sa, 2);
        sa += __shfl_xor(sa, 4);
        float pa = __expf(sa * SC);
        z += pa;
        acc.x += pa * v0.x; acc.y += pa * v0.y;
        acc.z += pa * v0.z; acc.w += pa * v0.w;
    }

    float inv = 1.f / (z + 1e-16f);
    float4 o = reinterpret_cast<float4*>(out)[(size_t)node * 32 + l];
    o.x += acc.x * inv; o.y += acc.y * inv;
    o.z += acc.z * inv; o.w += acc.w * inv;
    reinterpret_cast<float4*>(out)[(size_t)node * 32 + l] = o;
}

// ---------------------------------------------------------------------------
extern "C" void kernel_launch(void* const* d_in, const int* in_sizes, int n_in,
                              void* d_out, int out_size, void* d_ws, size_t ws_size,
                              hipStream_t stream)
{
    const float* x   = (const float*)d_in[0];
    const int*   ei  = (const int*)d_in[1];     // int32 on device (harness contract)
    const float* Wq  = (const float*)d_in[2];
    const float* bq  = (const float*)d_in[3];
    const float* Wk  = (const float*)d_in[4];
    const float* bk  = (const float*)d_in[5];
    const float* Wv  = (const float*)d_in[6];
    const float* bv  = (const float*)d_in[7];
    const float* Wsk = (const float*)d_in[8];
    const float* bsk = (const float*)d_in[9];
    float* out = (float*)d_out;

    const int N = in_sizes[0] / DIN;
    const int E = in_sizes[1] / 2;
    const int nb = (N + NPB - 1) / NPB;          // buckets (391 for N=100k)

    // workspace: qh | kvh | wt | pairs | sorted | counts | rowptr |
    //            bcnt | boff | bcur | partials | chunkoff
    _Float16* qh  = (_Float16*)d_ws;
    _Float16* kvh = qh + (size_t)N * DIN;        // N*256 halves
    _Float16* wt  = kvh + (size_t)N * 256;       // 128 KB
    uint2* pairs  = (uint2*)(wt + 4 * 16384);    // E * 8B
    int* sorted   = (int*)(pairs + (size_t)E);
    int* counts   = sorted + E;
    int* rowptr   = counts + N;
    int* bcnt     = rowptr + (N + 1);
    int* boff     = bcnt + 512;
    int* bcur     = boff + 513;
    int* partials = bcur + 512;
    int* chunkoff = partials + 256;

    hipMemsetAsync(bcnt, 0, 512 * sizeof(int), stream);

    prep_w<<<(4 * 16384 + 255) / 256, 256, 0, stream>>>(Wq, Wk, Wv, Wsk, wt);

    qkvs_all<<<(N + MT - 1) / MT, 256, 0, stream>>>(x, wt, bq, bk, bv, bsk,
                                                    qh, kvh, out, N);

    bucket_hist<<<256, 256, 0, stream>>>(ei, bcnt, E, nb);
    scan_buckets<<<1, 512, 0, stream>>>(bcnt, boff, bcur, nb);
    int sb = (E + 256 * EPB_IT - 1) / (256 * EPB_IT);
    bucket_scatter<<<sb, 256, 0, stream>>>(ei, bcur, pairs, E, nb);
    bucket_counts<<<nb, 256, 0, stream>>>(pairs, boff, counts, N);

    int nch = (N + CHUNK - 1) / CHUNK;
    chunk_sums<<<nch, 256, 0, stream>>>(counts, partials, N);
    scan_chunks<<<1, 256, 0, stream>>>(partials, chunkoff, nch);
    scan_write<<<nch, 256, 0, stream>>>(counts, chunkoff, rowptr, N);

    bucket_place<<<nb, 256, 0, stream>>>(pairs, boff, rowptr, sorted, N);

    int ab = (N * 32 + 255) / 256;
    node_aggregate<<<ab, 256, 0, stream>>>(qh, kvh, rowptr, sorted, out, N);
}

// Round 2
// 395.082 us; speedup vs baseline: 1.1091x; 1.0093x over previous
//
#include <hip/hip_runtime.h>

#define DIN 128
#define NHEADS 4
#define CH 32
#define MT 128          // GEMM rows per block
#define CHUNK 4096      // node-scan chunk per block
#define NPB 256         // nodes per bucket (bucket = dst >> 8)
#define EPB_IT 25       // edges per thread in bucket_scatter (block: 6400)

#define ST_H 136        // fp16 staging row stride (halves): 272B, 16B-aligned rows
#define ST_F 132        // fp32 staging row stride (floats): 528B, 16B-aligned rows

typedef _Float16 h8 __attribute__((ext_vector_type(8)));
typedef _Float16 h2 __attribute__((ext_vector_type(2)));
typedef float f4 __attribute__((ext_vector_type(4)));

// ---------------------------------------------------------------------------
// prep: W[k][n] fp32 -> Wt[mat][n][k] fp16
// ---------------------------------------------------------------------------
__global__ __launch_bounds__(256) void prep_w(
    const float* __restrict__ Wq, const float* __restrict__ Wk,
    const float* __restrict__ Wv, const float* __restrict__ Wsk,
    _Float16* __restrict__ wt)
{
    int i = blockIdx.x * 256 + threadIdx.x;
    if (i >= 4 * 16384) return;
    int mat = i >> 14;
    int rem = i & 16383;
    int n  = rem >> 7;
    int kk = rem & 127;
    const float* W = (mat == 0) ? Wq : (mat == 1) ? Wk : (mat == 2) ? Wv : Wsk;
    wt[i] = (_Float16)W[kk * 128 + n];
}

// ---------------------------------------------------------------------------
// Kernel 1: fused MFMA GEMM for all 4 mats in one block.
// ---------------------------------------------------------------------------
__global__ __launch_bounds__(256) void qkvs_all(
    const float* __restrict__ x, const _Float16* __restrict__ wt,
    const float* __restrict__ bq, const float* __restrict__ bk,
    const float* __restrict__ bv, const float* __restrict__ bsk,
    _Float16* __restrict__ qh, _Float16* __restrict__ kvh,
    float* __restrict__ outskip, int N)
{
    __shared__ _Float16 Sbuf[17408];     // 34.8 KB: A-tile (32 KB) then staging
    const int t = threadIdx.x;
    const int rowBase = blockIdx.x * MT;

    // ---- load A tile (fp32 -> fp16, XOR-swizzled, stride 128) ----
    for (int i = t; i < MT * 16; i += 256) {
        int r  = i >> 4;
        int c8 = i & 15;
        int gr = rowBase + r;
        _Float16 h[8];
        if (gr < N) {
            float4 f0 = reinterpret_cast<const float4*>(x)[(size_t)gr * 32 + c8 * 2];
            float4 f1 = reinterpret_cast<const float4*>(x)[(size_t)gr * 32 + c8 * 2 + 1];
            h[0] = (_Float16)f0.x; h[1] = (_Float16)f0.y;
            h[2] = (_Float16)f0.z; h[3] = (_Float16)f0.w;
            h[4] = (_Float16)f1.x; h[5] = (_Float16)f1.y;
            h[6] = (_Float16)f1.z; h[7] = (_Float16)f1.w;
        } else {
            #pragma unroll
            for (int j = 0; j < 8; ++j) h[j] = (_Float16)0.f;
        }
        *reinterpret_cast<uint4*>(&Sbuf[r * 128 + ((c8 ^ (r & 7)) << 3)]) =
            *reinterpret_cast<uint4*>(h);
    }
    __syncthreads();

    const int wid  = t >> 6;
    const int l    = t & 63;
    const int lm   = l & 15;
    const int quad = l >> 4;

    // ---- hoist A fragments to registers; Sbuf becomes free for staging ----
    h8 afrag[2][4];
    #pragma unroll
    for (int kq = 0; kq < 4; ++kq) {
        int c8 = kq * 4 + quad;
        afrag[0][kq] = *reinterpret_cast<const h8*>(
            &Sbuf[(wid * 32 + lm) * 128 + ((c8 ^ (lm & 7)) << 3)]);
        afrag[1][kq] = *reinterpret_cast<const h8*>(
            &Sbuf[(wid * 32 + 16 + lm) * 128 + ((c8 ^ (lm & 7)) << 3)]);
    }
    __syncthreads();   // all waves done reading A-tile before staging overwrites

    for (int mat = 0; mat < 4; ++mat) {
        const _Float16* __restrict__ Bsrc = wt + (size_t)mat * 16384;

        f4 acc[2][8];
        #pragma unroll
        for (int ms = 0; ms < 2; ++ms)
            #pragma unroll
            for (int nt = 0; nt < 8; ++nt)
                acc[ms][nt] = (f4){0.f, 0.f, 0.f, 0.f};

        #pragma unroll
        for (int kq = 0; kq < 4; ++kq) {
            const int k0 = (kq * 4 + quad) << 3;
            #pragma unroll
            for (int nt = 0; nt < 8; ++nt) {
                h8 b = *reinterpret_cast<const h8*>(
                    &Bsrc[(size_t)(nt * 16 + lm) * 128 + k0]);
                acc[0][nt] = __builtin_amdgcn_mfma_f32_16x16x32_f16(afrag[0][kq], b, acc[0][nt], 0, 0, 0);
                acc[1][nt] = __builtin_amdgcn_mfma_f32_16x16x32_f16(afrag[1][kq], b, acc[1][nt], 0, 0, 0);
            }
        }

        const float* bias = (mat == 0) ? bq : (mat == 1) ? bk : (mat == 2) ? bv : bsk;

        if (mat < 3) {
            // ---- stage fp16 tile [128][ST_H] ----
            #pragma unroll
            for (int ms = 0; ms < 2; ++ms) {
                #pragma unroll
                for (int nt = 0; nt < 8; ++nt) {
                    int col = nt * 16 + lm;
                    float bsv = bias[col];
                    int row = wid * 32 + ms * 16 + quad * 4;
                    #pragma unroll
                    for (int i2 = 0; i2 < 4; ++i2)
                        Sbuf[(row + i2) * ST_H + col] = (_Float16)(acc[ms][nt][i2] + bsv);
                }
            }
            __syncthreads();
            if (mat == 0) {
                // qh: 128 rows x 16 uint4, fully coalesced
                for (int j = t; j < 2048; j += 256) {
                    int r  = j >> 4;
                    int c0 = (j & 15) << 3;
                    int gr = rowBase + r;
                    if (gr < N)
                        *reinterpret_cast<uint4*>(&qh[(size_t)gr * 128 + c0]) =
                            *reinterpret_cast<const uint4*>(&Sbuf[r * ST_H + c0]);
                }
            } else {
                // kvh interleave: per row 32 uint2 chunks at stride 16B
                const int koff = (mat == 2) ? 4 : 0;
                for (int j = t; j < 4096; j += 256) {
                    int r = j >> 5;
                    int g = j & 31;
                    int gr = rowBase + r;
                    if (gr < N)
                        *reinterpret_cast<uint2*>(&kvh[(size_t)gr * 256 + g * 8 + koff]) =
                            *reinterpret_cast<const uint2*>(&Sbuf[r * ST_H + g * 4]);
                }
            }
            __syncthreads();   // staging buffer reused next mat
        } else {
            // ---- skip output is fp32: stage 64 rows per pass (2 passes) ----
            float* Sf = reinterpret_cast<float*>(Sbuf);
            #pragma unroll
            for (int p = 0; p < 2; ++p) {
                if ((wid >> 1) == p) {
                    int lrow = (wid & 1) * 32;
                    #pragma unroll
                    for (int ms = 0; ms < 2; ++ms) {
                        #pragma unroll
                        for (int nt = 0; nt < 8; ++nt) {
                            int col = nt * 16 + lm;
                            float bsv = bias[col];
                            int row = lrow + ms * 16 + quad * 4;
                            #pragma unroll
                            for (int i2 = 0; i2 < 4; ++i2)
                                Sf[(row + i2) * ST_F + col] = acc[ms][nt][i2] + bsv;
                        }
                    }
                }
                __syncthreads();
                for (int j = t; j < 2048; j += 256) {
                    int r  = j >> 5;
                    int c0 = (j & 31) << 2;
                    int gr = rowBase + p * 64 + r;
                    if (gr < N)
                        *reinterpret_cast<float4*>(&outskip[(size_t)gr * 128 + c0]) =
                            *reinterpret_cast<const float4*>(&Sf[r * ST_F + c0]);
                }
                __syncthreads();
            }
        }
    }
}

// ---------------------------------------------------------------------------
// Bucketed CSR build.  bucket b = nodes [b*256, b*256+256)
// ---------------------------------------------------------------------------
__global__ __launch_bounds__(256) void bucket_hist(
    const int* __restrict__ ei, int* __restrict__ bcnt, int E, int nb)
{
    __shared__ int lds[512];
    for (int b = threadIdx.x; b < nb; b += 256) lds[b] = 0;
    __syncthreads();
    for (long long i = (long long)blockIdx.x * 256 + threadIdx.x; i < E;
         i += (long long)gridDim.x * 256)
        atomicAdd(&lds[ei[(size_t)E + i] >> 8], 1);
    __syncthreads();
    for (int b = threadIdx.x; b < nb; b += 256)
        if (lds[b]) atomicAdd(&bcnt[b], lds[b]);
}

__global__ __launch_bounds__(512) void scan_buckets(
    const int* __restrict__ bcnt, int* __restrict__ boff,
    int* __restrict__ bcur, int nb)
{
    __shared__ int ws[8];
    int t = threadIdx.x, lane = t & 63, wid = t >> 6;
    int v = (t < nb) ? bcnt[t] : 0;
    int s = v;
    #pragma unroll
    for (int off = 1; off < 64; off <<= 1) {
        int n = __shfl_up(s, off);
        if (lane >= off) s += n;
    }
    if (lane == 63) ws[wid] = s;
    __syncthreads();
    int add = 0;
    for (int w = 0; w < wid; ++w) add += ws[w];
    int excl = s - v + add;
    if (t < nb) { boff[t] = excl; bcur[t] = excl; }
    if (t == nb - 1) boff[nb] = excl + v;
}

__global__ __launch_bounds__(256) void bucket_scatter(
    const int* __restrict__ ei, int* __restrict__ bcur,
    uint2* __restrict__ pairs, int E, int nb)
{
    __shared__ int cnt[512];
    int t = threadIdx.x;
    for (int b = t; b < nb; b += 256) cnt[b] = 0;
    __syncthreads();

    long long e0 = (long long)blockIdx.x * (256 * EPB_IT);
    int ps[EPB_IT], pd[EPB_IT];
    #pragma unroll
    for (int j = 0; j < EPB_IT; ++j) {
        long long e = e0 + j * 256 + t;
        if (e < E) {
            ps[j] = ei[e];
            pd[j] = ei[(size_t)E + e];
            atomicAdd(&cnt[pd[j] >> 8], 1);
        } else pd[j] = -1;
    }
    __syncthreads();
    for (int b = t; b < nb; b += 256) {
        int c = cnt[b];
        if (c) cnt[b] = atomicAdd(&bcur[b], c);
    }
    __syncthreads();
    #pragma unroll
    for (int j = 0; j < EPB_IT; ++j) {
        if (pd[j] >= 0) {
            int pos = atomicAdd(&cnt[pd[j] >> 8], 1);
            pairs[pos] = make_uint2((unsigned)ps[j], (unsigned)pd[j]);
        }
    }
}

__global__ __launch_bounds__(256) void bucket_counts(
    const uint2* __restrict__ pairs, const int* __restrict__ boff,
    int* __restrict__ counts, int N)
{
    __shared__ int cnt[NPB];
    int b = blockIdx.x, t = threadIdx.x;
    cnt[t] = 0;
    __syncthreads();
    int s = boff[b], e = boff[b + 1];
    for (int i = s + t; i < e; i += 256)
        atomicAdd(&cnt[pairs[i].y & (NPB - 1)], 1);
    __syncthreads();
    int node = b * NPB + t;
    if (node < N) counts[node] = cnt[t];
}

__global__ __launch_bounds__(256) void chunk_sums(
    const int* __restrict__ counts, int* __restrict__ partials, int N)
{
    int b = blockIdx.x, t = threadIdx.x;
    int base = b * CHUNK + t * 16;
    int s = 0;
    #pragma unroll
    for (int j = 0; j < 16; ++j) {
        int i = base + j;
        if (i < N) s += counts[i];
    }
    #pragma unroll
    for (int off = 1; off < 64; off <<= 1) s += __shfl_xor(s, off);
    __shared__ int ws[4];
    int lane = t & 63, wid = t >> 6;
    if (lane == 0) ws[wid] = s;
    __syncthreads();
    if (t == 0) partials[b] = ws[0] + ws[1] + ws[2] + ws[3];
}

__global__ __launch_bounds__(256) void scan_chunks(
    const int* __restrict__ partials, int* __restrict__ chunkoff, int nch)
{
    __shared__ int ws[4];
    int t = threadIdx.x, lane = t & 63, wid = t >> 6;
    int v = (t < nch) ? partials[t] : 0;
    int s = v;
    #pragma unroll
    for (int off = 1; off < 64; off <<= 1) {
        int n = __shfl_up(s, off);
        if (lane >= off) s += n;
    }
    if (lane == 63) ws[wid] = s;
    __syncthreads();
    int add = 0;
    for (int w = 0; w < wid; ++w) add += ws[w];
    if (t < nch) chunkoff[t] = s - v + add;
}

__global__ __launch_bounds__(256) void scan_write(
    const int* __restrict__ counts, const int* __restrict__ chunkoff,
    int* __restrict__ rowptr, int N)
{
    int b = blockIdx.x, t = threadIdx.x;
    int base = b * CHUNK + t * 16;
    int vals[16];
    int s = 0;
    #pragma unroll
    for (int j = 0; j < 16; ++j) {
        int i = base + j;
        vals[j] = (i < N) ? counts[i] : 0;
        s += vals[j];
    }
    int lane = t & 63, wid = t >> 6;
    int incl = s;
    #pragma unroll
    for (int off = 1; off < 64; off <<= 1) {
        int n = __shfl_up(incl, off);
        if (lane >= off) incl += n;
    }
    __shared__ int ws[4];
    if (lane == 63) ws[wid] = incl;
    __syncthreads();
    int add = chunkoff[b];
    for (int w = 0; w < wid; ++w) add += ws[w];
    int run = incl - s + add;
    #pragma unroll
    for (int j = 0; j < 16; ++j) {
        int i = base + j;
        if (i < N) rowptr[i + 1] = run + vals[j];
        run += vals[j];
    }
    if (b == 0 && t == 0) rowptr[0] = 0;
}

__global__ __launch_bounds__(256) void bucket_place(
    const uint2* __restrict__ pairs, const int* __restrict__ boff,
    const int* __restrict__ rowptr, int* __restrict__ sorted, int N)
{
    __shared__ int cur[NPB];
    int b = blockIdx.x, t = threadIdx.x;
    int node = b * NPB + t;
    cur[t] = (node < N) ? rowptr[node] : 0;
    __syncthreads();
    int s = boff[b], e = boff[b + 1];
    for (int i = s + t; i < e; i += 256) {
        uint2 pr = pairs[i];
        int pos = atomicAdd(&cur[pr.y & (NPB - 1)], 1);
        sorted[pos] = (int)pr.x;
    }
}

// ---------------------------------------------------------------------------
// Kernel 4: fused logits + softmax + aggregation.
//   8-edge unroll (MLP to hide gather latency) + v_dot2_f32_f16 logits.
// ---------------------------------------------------------------------------
__device__ inline float4 cvt4(uint2 r) {
    union { uint2 u; _Float16 h[4]; } c;
    c.u = r;
    return make_float4((float)c.h[0], (float)c.h[1], (float)c.h[2], (float)c.h[3]);
}

__device__ inline h2 as_h2(unsigned u) {
    union { unsigned u; h2 h; } c;
    c.u = u;
    return c.h;
}

__global__ __launch_bounds__(256) void node_aggregate(
    const _Float16* __restrict__ q, const _Float16* __restrict__ kv,
    const int* __restrict__ rowptr, const int* __restrict__ srcs,
    float* __restrict__ out, int N)
{
    int gid  = blockIdx.x * 256 + threadIdx.x;
    int node = gid >> 5;
    if (node >= N) return;
    int l = gid & 31;

    // q fragment for this lane: 4 halves, kept packed for fdot2
    uint2 qu = reinterpret_cast<const uint2*>(q + (size_t)node * 128)[l];
    h2 qa = as_h2(qu.x), qb = as_h2(qu.y);

    float4 acc = make_float4(0.f, 0.f, 0.f, 0.f);
    float z = 0.f;

    const uint4* kv4 = reinterpret_cast<const uint4*>(kv);
    const float SC = 0.17677669529663687f;   // 1/sqrt(32)
    int e0 = rowptr[node], e1 = rowptr[node + 1];
    int e = e0;

    for (; e + 8 <= e1; e += 8) {
        int s[8];
        #pragma unroll
        for (int j = 0; j < 8; ++j) s[j] = srcs[e + j];
        uint4 r[8];
        #pragma unroll
        for (int j = 0; j < 8; ++j) r[j] = kv4[(size_t)s[j] * 32 + l];

        float sv[8];
        #pragma unroll
        for (int j = 0; j < 8; ++j) {
            sv[j] = __builtin_amdgcn_fdot2(qa, as_h2(r[j].x),
                    __builtin_amdgcn_fdot2(qb, as_h2(r[j].y), 0.f, false), false);
        }
        #pragma unroll
        for (int j = 0; j < 8; ++j) sv[j] += __shfl_xor(sv[j], 1);
        #pragma unroll
        for (int j = 0; j < 8; ++j) sv[j] += __shfl_xor(sv[j], 2);
        #pragma unroll
        for (int j = 0; j < 8; ++j) sv[j] += __shfl_xor(sv[j], 4);

        #pragma unroll
        for (int j = 0; j < 8; ++j) {
            float p = __expf(sv[j] * SC);
            float4 v = cvt4(make_uint2(r[j].z, r[j].w));
            z += p;
            acc.x += p * v.x; acc.y += p * v.y;
            acc.z += p * v.z; acc.w += p * v.w;
        }
    }
    for (; e + 4 <= e1; e += 4) {
        int s0 = srcs[e], s1 = srcs[e + 1], s2 = srcs[e + 2], s3 = srcs[e + 3];
        uint4 r0 = kv4[(size_t)s0 * 32 + l];
        uint4 r1 = kv4[(size_t)s1 * 32 + l];
        uint4 r2 = kv4[(size_t)s2 * 32 + l];
        uint4 r3 = kv4[(size_t)s3 * 32 + l];
        float sa = __builtin_amdgcn_fdot2(qa, as_h2(r0.x),
                   __builtin_amdgcn_fdot2(qb, as_h2(r0.y), 0.f, false), false);
        float sb = __builtin_amdgcn_fdot2(qa, as_h2(r1.x),
                   __builtin_amdgcn_fdot2(qb, as_h2(r1.y), 0.f, false), false);
        float sc = __builtin_amdgcn_fdot2(qa, as_h2(r2.x),
                   __builtin_amdgcn_fdot2(qb, as_h2(r2.y), 0.f, false), false);
        float sd = __builtin_amdgcn_fdot2(qa, as_h2(r3.x),
                   __builtin_amdgcn_fdot2(qb, as_h2(r3.y), 0.f, false), false);
        sa += __shfl_xor(sa, 1); sb += __shfl_xor(sb, 1);
        sc += __shfl_xor(sc, 1); sd += __shfl_xor(sd, 1);
        sa += __shfl_xor(sa, 2); sb += __shfl_xor(sb, 2);
        sc += __shfl_xor(sc, 2); sd += __shfl_xor(sd, 2);
        sa += __shfl_xor(sa, 4); sb += __shfl_xor(sb, 4);
        sc += __shfl_xor(sc, 4); sd += __shfl_xor(sd, 4);
        float pa = __expf(sa * SC), pb = __expf(sb * SC);
        float pc = __expf(sc * SC), pdd = __expf(sd * SC);
        float4 v0 = cvt4(make_uint2(r0.z, r0.w));
        float4 v1 = cvt4(make_uint2(r1.z, r1.w));
        float4 v2 = cvt4(make_uint2(r2.z, r2.w));
        float4 v3 = cvt4(make_uint2(r3.z, r3.w));
        z += (pa + pb) + (pc + pdd);
        acc.x += pa * v0.x + pb * v1.x + pc * v2.x + pdd * v3.x;
        acc.y += pa * v0.y + pb * v1.y + pc * v2.y + pdd * v3.y;
        acc.z += pa * v0.z + pb * v1.z + pc * v2.z + pdd * v3.z;
        acc.w += pa * v0.w + pb * v1.w + pc * v2.w + pdd * v3.w;
    }
    for (; e < e1; ++e) {
        int s0 = srcs[e];
        uint4 r0 = kv4[(size_t)s0 * 32 + l];
        float sa = __builtin_amdgcn_fdot2(qa, as_h2(r0.x),
                   __builtin_amdgcn_fdot2(qb, as_h2(r0.y), 0.f, false), false);
        sa += __shfl_xor(sa, 1);
        sa += __shfl_xor(sa, 2);
        sa += __shfl_xor(sa, 4);
        float pa = __expf(sa * SC);
        float4 v0 = cvt4(make_uint2(r0.z, r0.w));
        z += pa;
        acc.x += pa * v0.x; acc.y += pa * v0.y;
        acc.z += pa * v0.z; acc.w += pa * v0.w;
    }

    float inv = 1.f / (z + 1e-16f);
    float4 o = reinterpret_cast<float4*>(out)[(size_t)node * 32 + l];
    o.x += acc.x * inv; o.y += acc.y * inv;
    o.z += acc.z * inv; o.w += acc.w * inv;
    reinterpret_cast<float4*>(out)[(size_t)node * 32 + l] = o;
}

// ---------------------------------------------------------------------------
extern "C" void kernel_launch(void* const* d_in, const int* in_sizes, int n_in,
                              void* d_out, int out_size, void* d_ws, size_t ws_size,
                              hipStream_t stream)
{
    const float* x   = (const float*)d_in[0];
    const int*   ei  = (const int*)d_in[1];     // int32 on device (harness contract)
    const float* Wq  = (const float*)d_in[2];
    const float* bq  = (const float*)d_in[3];
    const float* Wk  = (const float*)d_in[4];
    const float* bk  = (const float*)d_in[5];
    const float* Wv  = (const float*)d_in[6];
    const float* bv  = (const float*)d_in[7];
    const float* Wsk = (const float*)d_in[8];
    const float* bsk = (const float*)d_in[9];
    float* out = (float*)d_out;

    const int N = in_sizes[0] / DIN;
    const int E = in_sizes[1] / 2;
    const int nb = (N + NPB - 1) / NPB;          // buckets (391 for N=100k)

    // workspace: qh | kvh | wt | pairs | sorted | counts | rowptr |
    //            bcnt | boff | bcur | partials | chunkoff
    _Float16* qh  = (_Float16*)d_ws;
    _Float16* kvh = qh + (size_t)N * DIN;        // N*256 halves
    _Float16* wt  = kvh + (size_t)N * 256;       // 128 KB
    uint2* pairs  = (uint2*)(wt + 4 * 16384);    // E * 8B
    int* sorted   = (int*)(pairs + (size_t)E);
    int* counts   = sorted + E;
    int* rowptr   = counts + N;
    int* bcnt     = rowptr + (N + 1);
    int* boff     = bcnt + 512;
    int* bcur     = boff + 513;
    int* partials = bcur + 512;
    int* chunkoff = partials + 256;

    hipMemsetAsync(bcnt, 0, 512 * sizeof(int), stream);

    prep_w<<<(4 * 16384 + 255) / 256, 256, 0, stream>>>(Wq, Wk, Wv, Wsk, wt);

    qkvs_all<<<(N + MT - 1) / MT, 256, 0, stream>>>(x, wt, bq, bk, bv, bsk,
                                                    qh, kvh, out, N);

    bucket_hist<<<256, 256, 0, stream>>>(ei, bcnt, E, nb);
    scan_buckets<<<1, 512, 0, stream>>>(bcnt, boff, bcur, nb);
    int sb = (E + 256 * EPB_IT - 1) / (256 * EPB_IT);
    bucket_scatter<<<sb, 256, 0, stream>>>(ei, bcur, pairs, E, nb);
    bucket_counts<<<nb, 256, 0, stream>>>(pairs, boff, counts, N);

    int nch = (N + CHUNK - 1) / CHUNK;
    chunk_sums<<<nch, 256, 0, stream>>>(counts, partials, N);
    scan_chunks<<<1, 256, 0, stream>>>(partials, chunkoff, nch);
    scan_write<<<nch, 256, 0, stream>>>(counts, chunkoff, rowptr, N);

    bucket_place<<<nb, 256, 0, stream>>>(pairs, boff, rowptr, sorted, N);

    int ab = (N * 32 + 255) / 256;
    node_aggregate<<<ab, 256, 0, stream>>>(qh, kvh, rowptr, sorted, out, N);
}